// Round 4
// baseline (684.772 us; speedup 1.0000x reference)
//
#include <hip/hip_runtime.h>
#include <hip/hip_bf16.h>

// Jacobian of MLP 3->64->64->64->64->12 via 3 forward tangents, batched as
// 4 streams (h,t0,t1,t2) per point through bf16 MFMA (32x32x16).
//
// R4 changes vs R3 (VALU-bound, 601us, VALUBusy 82 / Mfma 18.5 / Occ 31):
//  1. silu sg/d via LDS lerp-LUT (513 knots, (val,slope) float2; per-lane
//     base ptr picks sg- or d-table) -- removes expf/rcp trans ops and the
//     long serial chains; table reads are quad-broadcast (2 addrs/quad = free).
//  2. Sequential N-tiles (cols 0-31 then 32-63): acc regs 64->32, target
//     <=128 VGPR for 4 waves/SIMD (launch_bounds(256,4)); LDS 39.9KB = 4
//     blocks/CU. A-fragments read twice per layer (LDS pipe has headroom).

#define THREADS 256

typedef float  f32x16 __attribute__((ext_vector_type(16)));
typedef float  f32x4  __attribute__((ext_vector_type(4)));
typedef short  s16x8  __attribute__((ext_vector_type(8)));

#define MFMA(a, b, c) __builtin_amdgcn_mfma_f32_32x32x16_bf16(a, b, c, 0, 0, 0)

__device__ __forceinline__ uint cvtpk(float a, float b) {
    uint r;
    asm("v_cvt_pk_bf16_f32 %0, %1, %2" : "=v"(r) : "v"(a), "v"(b));
    return r;
}
__device__ __forceinline__ void plswap(uint &a, uint &b) {
    asm("v_permlane32_swap_b32 %0, %1" : "+v"(a), "+v"(b));
}
__device__ __forceinline__ float quad0(float v) {  // broadcast quad-lane 0
    return __int_as_float(__builtin_amdgcn_mov_dpp(__float_as_int(v), 0, 0xF, 0xF, false));
}
__device__ __forceinline__ ushort bfhi(float v) {  // bf16 RNE
    uint u = __float_as_uint(v);
    return (ushort)((u + 0x7FFFu + ((u >> 16) & 1u)) >> 16);
}
__device__ __forceinline__ s16x8 mk8(uint a, uint b, uint c, uint d) {
    union { uint u[4]; s16x8 s; } x;
    x.u[0] = a; x.u[1] = b; x.u[2] = c; x.u[3] = d;
    return x.s;
}
__device__ __forceinline__ void pack_pairs(const f32x16 &A, const int i0,
                                           uint (&H)[4], uint (&L)[4]) {
    #pragma unroll
    for (int q = 0; q < 4; ++q) {
        float v0 = A[i0 + 2 * q], v1 = A[i0 + 2 * q + 1];
        uint  Hc = cvtpk(v0, v1);
        float r0 = v0 - __uint_as_float(Hc << 16);
        float r1 = v1 - __uint_as_float(Hc & 0xFFFF0000u);
        H[q] = Hc;
        L[q] = cvtpk(r0, r1);
    }
    plswap(H[0], H[2]); plswap(H[1], H[3]);
    plswap(L[0], L[2]); plswap(L[1], L[3]);
}

__global__ __launch_bounds__(THREADS, 4)
void PartialDerivatives_mfma(const float* __restrict__ x,
                             const float* __restrict__ W1, const float* __restrict__ b1,
                             const float* __restrict__ W2, const float* __restrict__ b2,
                             const float* __restrict__ W3, const float* __restrict__ b3,
                             const float* __restrict__ W4, const float* __restrict__ b4,
                             const float* __restrict__ W5,
                             float* __restrict__ out, int N, int ntiles)
{
    // Fragment-ordered weight staging (conflict-free ds_read_b128 per lane).
    __shared__ __align__(16) ushort sWH[3 * 2 * 4 * 64 * 8]; // W2..W4^T, 24576 B
    __shared__ __align__(16) ushort sW1[2 * 64 * 8];         // W1^T (k<3),  2048 B
    __shared__ __align__(16) ushort sW5[4 * 64 * 8];         // W5^T (pad m), 4096 B
    __shared__ __align__(16) float  sB[4 * 64];              // b1..b4 f32,  1024 B
    __shared__ __align__(8)  float2 sTab[2][513];            // [0]=sg [1]=d, 8208 B

    const int tid = threadIdx.x;
    for (int i = tid; i < 12288; i += THREADS) {
        int e = i & 7, lane = (i >> 3) & 63, kk = (i >> 9) & 3, mt = (i >> 11) & 1, l = i >> 12;
        int n = mt * 32 + (lane & 31);
        int k = kk * 16 + (lane >> 5) * 8 + e;
        const float* W = (l == 0) ? W2 : (l == 1) ? W3 : W4;
        sWH[i] = bfhi(W[k * 64 + n]);           // A[n][k] = W[k][n]
    }
    for (int i = tid; i < 1024; i += THREADS) {
        int e = i & 7, lane = (i >> 3) & 63, mt = i >> 9;
        int n = mt * 32 + (lane & 31);
        int k = (lane >> 5) * 8 + e;
        sW1[i] = (k < 3) ? bfhi(W1[k * 64 + n]) : (ushort)0;
    }
    for (int i = tid; i < 2048; i += THREADS) {
        int e = i & 7, lane = (i >> 3) & 63, kk = i >> 9;
        int m = lane & 31;
        int k = kk * 16 + (lane >> 5) * 8 + e;
        sW5[i] = (m < 12) ? bfhi(W5[k * 12 + m]) : (ushort)0;
    }
    if (tid < 64) {
        sB[tid] = b1[tid]; sB[64 + tid] = b2[tid];
        sB[128 + tid] = b3[tid]; sB[192 + tid] = b4[tid];
    }
    // silu LUT: z in [-10,10], 512 intervals; entry = (y_i, y_{i+1}-y_i).
    for (int i = tid; i < 1026; i += THREADS) {
        int  c  = (i >= 513);
        int  k  = c ? i - 513 : i;
        float z0 = -10.f + k * 0.0390625f;
        float z1 = z0 + 0.0390625f;
        float s0 = 1.f / (1.f + __expf(-z0));
        float s1 = 1.f / (1.f + __expf(-z1));
        float y0 = c ? s0 * (1.f + z0 * (1.f - s0)) : s0;
        float y1 = c ? s1 * (1.f + z1 * (1.f - s1)) : s1;
        sTab[c][k] = make_float2(y0, y1 - y0);
    }
    __syncthreads();

    const int  lane = tid & 63;
    const int  hi   = lane >> 5;
    const int  s    = lane & 3;          // stream: 0=h, 1..3=tangent xyz
    const bool is0  = (s == 0);
    const int  pq   = (lane & 31) >> 2;  // point within half-tile, 0..7
    const float2* __restrict__ tb = &sTab[is0 ? 0 : 1][0];

    const int wid = blockIdx.x * (THREADS / 64) + (tid >> 6);
    const int nw  = gridDim.x * (THREADS / 64);

    // scale col's acc by LUT(sg|d)(z of quad leader)
#define SILU16(A)                                                              \
    { _Pragma("unroll")                                                        \
      for (int i = 0; i < 16; ++i) {                                           \
          float zb = quad0(A[i]);                                              \
          float zc = fminf(fmaxf(zb, -10.f), 10.f);                            \
          float u  = __builtin_fmaf(zc, 25.6f, 256.0f);                        \
          float fl = floorf(u);                                                \
          float fr = u - fl;                                                   \
          float2 e = tb[(int)fl];                                              \
          A[i] *= __builtin_fmaf(e.y, fr, e.x);                                \
      } }

#define EPILOGUE_NT(nt, aLo, aHi)                                              \
    {   SILU16(aLo); SILU16(aHi);                                              \
        pack_pairs(aLo, 0, Bh[0][nt], Bl[0][nt]);                              \
        pack_pairs(aLo, 8, Bh[1][nt], Bl[1][nt]);                              \
        pack_pairs(aHi, 0, Bh[2][nt], Bl[2][nt]);                              \
        pack_pairs(aHi, 8, Bh[3][nt], Bl[3][nt]); }

#define BINIT(boff, aLo, aHi)                                                  \
    { _Pragma("unroll")                                                        \
      for (int q = 0; q < 4; ++q) {                                            \
          f32x4 bb0 = *(const f32x4*)&sB[(boff) + q * 8 + hi * 4];             \
          f32x4 bb1 = *(const f32x4*)&sB[(boff) + 32 + q * 8 + hi * 4];        \
          _Pragma("unroll")                                                    \
          for (int j = 0; j < 4; ++j) {                                        \
              aLo[q * 4 + j] = bb0[j]; aHi[q * 4 + j] = bb1[j];                \
          } } }

    #pragma unroll 1
    for (int t = wid; t < ntiles; t += nw) {
        const int base = t * 16;
        uint Bh[4][2][4], Bl[4][2][4];

        // ---------------- Layer 1 (K=16, rows 0..2 = W1, bias via init) ----
        #pragma unroll
        for (int nt = 0; nt < 2; ++nt) {
            f32x16 aLo, aHi;
            BINIT(0, aLo, aHi);
            uint h0 = 0u, h1 = 0u, l0 = 0u, l1 = 0u;
            if (hi == 0) {
                if (is0) {
                    int pt = base + nt * 8 + pq;
                    if (pt > N - 1) pt = N - 1;
                    const float* xp = x + (size_t)pt * 3;
                    float x0 = xp[0], x1 = xp[1], x2 = xp[2];
                    h0 = cvtpk(x0, x1);
                    h1 = cvtpk(x2, 0.f);
                    float r0 = x0 - __uint_as_float(h0 << 16);
                    float r1 = x1 - __uint_as_float(h0 & 0xFFFF0000u);
                    float r2 = x2 - __uint_as_float(h1 << 16);
                    l0 = cvtpk(r0, r1); l1 = cvtpk(r2, 0.f);
                } else {
                    // one-hot tangent basis e_{s-1} (exact in bf16)
                    h0 = (s == 1) ? 0x3F80u : (s == 2) ? 0x3F800000u : 0u;
                    h1 = (s == 3) ? 0x3F80u : 0u;
                }
            }
            s16x8 A0  = *(const s16x8*)&sW1[0 * 512 + lane * 8];
            s16x8 A1  = *(const s16x8*)&sW1[1 * 512 + lane * 8];
            s16x8 bh  = mk8(h0, h1, 0u, 0u);
            s16x8 bl  = mk8(l0, l1, 0u, 0u);
            aLo = MFMA(A0, bh, aLo); aLo = MFMA(A0, bl, aLo);
            aHi = MFMA(A1, bh, aHi); aHi = MFMA(A1, bl, aHi);
            EPILOGUE_NT(nt, aLo, aHi);
        }

        // ---------------- Hidden layers 2..4 (sequential N-tiles) ---------
        #pragma unroll 1
        for (int l = 0; l < 3; ++l) {
            #pragma unroll
            for (int nt = 0; nt < 2; ++nt) {
                f32x16 aLo, aHi;
                BINIT((l + 1) * 64, aLo, aHi);
                #pragma unroll
                for (int kk = 0; kk < 4; ++kk) {
                    s16x8 A0 = *(const s16x8*)&sWH[((l * 2 + 0) * 4 + kk) * 512 + lane * 8];
                    s16x8 A1 = *(const s16x8*)&sWH[((l * 2 + 1) * 4 + kk) * 512 + lane * 8];
                    s16x8 bh = mk8(Bh[kk][nt][0], Bh[kk][nt][1], Bh[kk][nt][2], Bh[kk][nt][3]);
                    s16x8 bl = mk8(Bl[kk][nt][0], Bl[kk][nt][1], Bl[kk][nt][2], Bl[kk][nt][3]);
                    aLo = MFMA(A0, bh, aLo); aLo = MFMA(A0, bl, aLo);
                    aHi = MFMA(A1, bh, aHi); aHi = MFMA(A1, bl, aHi);
                }
                EPILOGUE_NT(nt, aLo, aHi);   // overwrites B[*][nt] (dead slots)
            }
        }

        // ---------------- Output layer (M=12 padded to 32, no bias) -------
        #pragma unroll
        for (int nt = 0; nt < 2; ++nt) {
            f32x16 o;
            #pragma unroll
            for (int i = 0; i < 16; ++i) o[i] = 0.f;
            #pragma unroll
            for (int kk = 0; kk < 4; ++kk) {
                s16x8 A5 = *(const s16x8*)&sW5[kk * 512 + lane * 8];
                s16x8 bh = mk8(Bh[kk][nt][0], Bh[kk][nt][1], Bh[kk][nt][2], Bh[kk][nt][3]);
                s16x8 bl = mk8(Bl[kk][nt][0], Bl[kk][nt][1], Bl[kk][nt][2], Bl[kk][nt][3]);
                o = MFMA(A5, bh, o); o = MFMA(A5, bl, o);
            }
            // col r=4p+s, s>0 -> out[pt][s-1][m]; m = (i&3)+8*(i>>2)+4*hi
            if (!is0) {
                int pt = base + nt * 8 + pq;
                if (pt < N) {
                    float* ob = out + (size_t)pt * 36 + (s - 1) * 12;
                    if (hi == 0) {
                        *(f32x4*)(ob + 0) = (f32x4){o[0], o[1], o[2], o[3]};
                        *(f32x4*)(ob + 8) = (f32x4){o[4], o[5], o[6], o[7]};
                    } else {
                        *(f32x4*)(ob + 4) = (f32x4){o[0], o[1], o[2], o[3]};
                    }
                }
            }
        }
    }
#undef SILU16
#undef EPILOGUE_NT
#undef BINIT
}

extern "C" void kernel_launch(void* const* d_in, const int* in_sizes, int n_in,
                              void* d_out, int out_size, void* d_ws, size_t ws_size,
                              hipStream_t stream) {
    const float* x  = (const float*)d_in[0];
    const float* W1 = (const float*)d_in[1];
    const float* b1 = (const float*)d_in[2];
    const float* W2 = (const float*)d_in[3];
    const float* b2 = (const float*)d_in[4];
    const float* W3 = (const float*)d_in[5];
    const float* b3 = (const float*)d_in[6];
    const float* W4 = (const float*)d_in[7];
    const float* b4 = (const float*)d_in[8];
    const float* W5 = (const float*)d_in[9];
    // d_in[10] = b5: unused (bias has zero Jacobian)
    float* out = (float*)d_out;

    const int N = in_sizes[0] / 3;
    const int ntiles = (N + 15) / 16;
    const int blocks = 2048;
    PartialDerivatives_mfma<<<blocks, THREADS, 0, stream>>>(
        x, W1, b1, W2, b2, W3, b3, W4, b4, W5, out, N, ntiles);
}

// Round 5
// 618.363 us; speedup vs baseline: 1.1074x; 1.1074x over previous
//
#include <hip/hip_runtime.h>
#include <hip/hip_bf16.h>

// Jacobian of MLP 3->64->64->64->64->12 via 3 forward tangents, batched as
// 4 streams (h,t0,t1,t2) per point through bf16 MFMA (32x32x16).
//
// R5 change vs R4 (610us, VGPR 64 + massive scratch spill traffic):
//  DEPTH-FIRST N-tiles: each 32-col half-tile (8 points) runs through ALL
//  layers before the second half starts. Persistent B-state halves
//  (Bh[4][4]+Bl[4][4] = 32 regs vs 64) -> fits the launch_bounds(256,4)
//  128-VGPR cap without spilling. Keeps R4's silu lerp-LUT (no trans ops)
//  and 4-blocks/CU LDS footprint (40.4 KB).

#define THREADS 256

typedef float  f32x16 __attribute__((ext_vector_type(16)));
typedef float  f32x4  __attribute__((ext_vector_type(4)));
typedef short  s16x8  __attribute__((ext_vector_type(8)));

#define MFMA(a, b, c) __builtin_amdgcn_mfma_f32_32x32x16_bf16(a, b, c, 0, 0, 0)

__device__ __forceinline__ uint cvtpk(float a, float b) {
    uint r;
    asm("v_cvt_pk_bf16_f32 %0, %1, %2" : "=v"(r) : "v"(a), "v"(b));
    return r;
}
__device__ __forceinline__ void plswap(uint &a, uint &b) {
    asm("v_permlane32_swap_b32 %0, %1" : "+v"(a), "+v"(b));
}
__device__ __forceinline__ float quad0(float v) {  // broadcast quad-lane 0
    return __int_as_float(__builtin_amdgcn_mov_dpp(__float_as_int(v), 0, 0xF, 0xF, false));
}
__device__ __forceinline__ ushort bfhi(float v) {  // bf16 RNE
    uint u = __float_as_uint(v);
    return (ushort)((u + 0x7FFFu + ((u >> 16) & 1u)) >> 16);
}
__device__ __forceinline__ s16x8 mk8(uint a, uint b, uint c, uint d) {
    union { uint u[4]; s16x8 s; } x;
    x.u[0] = a; x.u[1] = b; x.u[2] = c; x.u[3] = d;
    return x.s;
}
__device__ __forceinline__ void pack_pairs(const f32x16 &A, const int i0,
                                           uint (&H)[4], uint (&L)[4]) {
    #pragma unroll
    for (int q = 0; q < 4; ++q) {
        float v0 = A[i0 + 2 * q], v1 = A[i0 + 2 * q + 1];
        uint  Hc = cvtpk(v0, v1);
        float r0 = v0 - __uint_as_float(Hc << 16);
        float r1 = v1 - __uint_as_float(Hc & 0xFFFF0000u);
        H[q] = Hc;
        L[q] = cvtpk(r0, r1);
    }
    plswap(H[0], H[2]); plswap(H[1], H[3]);
    plswap(L[0], L[2]); plswap(L[1], L[3]);
}

__global__ __launch_bounds__(THREADS, 4)
void PartialDerivatives_mfma(const float* __restrict__ x,
                             const float* __restrict__ W1, const float* __restrict__ b1,
                             const float* __restrict__ W2, const float* __restrict__ b2,
                             const float* __restrict__ W3, const float* __restrict__ b3,
                             const float* __restrict__ W4, const float* __restrict__ b4,
                             const float* __restrict__ W5,
                             float* __restrict__ out, int N, int ntiles)
{
    // Fragment-ordered weight staging (conflict-free ds_read_b128 per lane).
    __shared__ __align__(16) ushort sWH[3 * 2 * 4 * 64 * 8]; // W2..W4^T, 24576 B
    __shared__ __align__(16) ushort sW1[2 * 64 * 8];         // W1^T (k<3),  2048 B
    __shared__ __align__(16) ushort sW5[4 * 64 * 8];         // W5^T (pad m), 4096 B
    __shared__ __align__(16) float  sB[4 * 64];              // b1..b4 f32,  1024 B
    __shared__ __align__(8)  float2 sTab[2][513];            // [0]=sg [1]=d, 8208 B

    const int tid = threadIdx.x;
    for (int i = tid; i < 12288; i += THREADS) {
        int e = i & 7, lane = (i >> 3) & 63, kk = (i >> 9) & 3, mt = (i >> 11) & 1, l = i >> 12;
        int n = mt * 32 + (lane & 31);
        int k = kk * 16 + (lane >> 5) * 8 + e;
        const float* W = (l == 0) ? W2 : (l == 1) ? W3 : W4;
        sWH[i] = bfhi(W[k * 64 + n]);           // A[n][k] = W[k][n]
    }
    for (int i = tid; i < 1024; i += THREADS) {
        int e = i & 7, lane = (i >> 3) & 63, mt = i >> 9;
        int n = mt * 32 + (lane & 31);
        int k = (lane >> 5) * 8 + e;
        sW1[i] = (k < 3) ? bfhi(W1[k * 64 + n]) : (ushort)0;
    }
    for (int i = tid; i < 2048; i += THREADS) {
        int e = i & 7, lane = (i >> 3) & 63, kk = i >> 9;
        int m = lane & 31;
        int k = kk * 16 + (lane >> 5) * 8 + e;
        sW5[i] = (m < 12) ? bfhi(W5[k * 12 + m]) : (ushort)0;
    }
    if (tid < 64) {
        sB[tid] = b1[tid]; sB[64 + tid] = b2[tid];
        sB[128 + tid] = b3[tid]; sB[192 + tid] = b4[tid];
    }
    // silu LUT: z in [-10,10], 512 intervals; entry = (y_i, y_{i+1}-y_i).
    for (int i = tid; i < 1026; i += THREADS) {
        int  c  = (i >= 513);
        int  k  = c ? i - 513 : i;
        float z0 = -10.f + k * 0.0390625f;
        float z1 = z0 + 0.0390625f;
        float s0 = 1.f / (1.f + __expf(-z0));
        float s1 = 1.f / (1.f + __expf(-z1));
        float y0 = c ? s0 * (1.f + z0 * (1.f - s0)) : s0;
        float y1 = c ? s1 * (1.f + z1 * (1.f - s1)) : s1;
        sTab[c][k] = make_float2(y0, y1 - y0);
    }
    __syncthreads();

    const int  lane = tid & 63;
    const int  hi   = lane >> 5;
    const int  s    = lane & 3;          // stream: 0=h, 1..3=tangent xyz
    const bool is0  = (s == 0);
    const int  pq   = (lane & 31) >> 2;  // point within half-tile, 0..7
    const float2* __restrict__ tb = &sTab[is0 ? 0 : 1][0];

    const int wid = blockIdx.x * (THREADS / 64) + (tid >> 6);
    const int nw  = gridDim.x * (THREADS / 64);

    // scale col's acc by LUT(sg|d)(z of quad leader)
#define SILU16(A)                                                              \
    { _Pragma("unroll")                                                        \
      for (int i = 0; i < 16; ++i) {                                           \
          float zb = quad0(A[i]);                                              \
          float zc = fminf(fmaxf(zb, -10.f), 10.f);                            \
          float u  = __builtin_fmaf(zc, 25.6f, 256.0f);                        \
          float fl = floorf(u);                                                \
          float fr = u - fl;                                                   \
          float2 e = tb[(int)fl];                                              \
          A[i] *= __builtin_fmaf(e.y, fr, e.x);                                \
      } }

#define EPILOGUE()                                                             \
    {   SILU16(aLo); SILU16(aHi);                                              \
        pack_pairs(aLo, 0, Bh[0], Bl[0]);                                      \
        pack_pairs(aLo, 8, Bh[1], Bl[1]);                                      \
        pack_pairs(aHi, 0, Bh[2], Bl[2]);                                      \
        pack_pairs(aHi, 8, Bh[3], Bl[3]); }

#define BINIT(boff)                                                            \
    { _Pragma("unroll")                                                        \
      for (int q = 0; q < 4; ++q) {                                            \
          f32x4 bb0 = *(const f32x4*)&sB[(boff) + q * 8 + hi * 4];             \
          f32x4 bb1 = *(const f32x4*)&sB[(boff) + 32 + q * 8 + hi * 4];        \
          _Pragma("unroll")                                                    \
          for (int j = 0; j < 4; ++j) {                                        \
              aLo[q * 4 + j] = bb0[j]; aHi[q * 4 + j] = bb1[j];                \
          } } }

    #pragma unroll 1
    for (int t = wid; t < ntiles; t += nw) {
        const int base = t * 16;

        // Depth-first over the two 32-col half-tiles (8 points each):
        // full network per half-tile -> half the live B-state, no spills.
        #pragma unroll
        for (int nt = 0; nt < 2; ++nt) {
            uint Bh[4][4], Bl[4][4];
            f32x16 aLo, aHi;

            // ---------------- Layer 1 (K=16, rows 0..2 = W1) --------------
            BINIT(0);
            {
                uint h0 = 0u, h1 = 0u, l0 = 0u, l1 = 0u;
                if (hi == 0) {
                    if (is0) {
                        int pt = base + nt * 8 + pq;
                        if (pt > N - 1) pt = N - 1;
                        const float* xp = x + (size_t)pt * 3;
                        float x0 = xp[0], x1 = xp[1], x2 = xp[2];
                        h0 = cvtpk(x0, x1);
                        h1 = cvtpk(x2, 0.f);
                        float r0 = x0 - __uint_as_float(h0 << 16);
                        float r1 = x1 - __uint_as_float(h0 & 0xFFFF0000u);
                        float r2 = x2 - __uint_as_float(h1 << 16);
                        l0 = cvtpk(r0, r1); l1 = cvtpk(r2, 0.f);
                    } else {
                        // one-hot tangent basis e_{s-1} (exact in bf16)
                        h0 = (s == 1) ? 0x3F80u : (s == 2) ? 0x3F800000u : 0u;
                        h1 = (s == 3) ? 0x3F80u : 0u;
                    }
                }
                s16x8 A0 = *(const s16x8*)&sW1[0 * 512 + lane * 8];
                s16x8 A1 = *(const s16x8*)&sW1[1 * 512 + lane * 8];
                s16x8 bh = mk8(h0, h1, 0u, 0u);
                s16x8 bl = mk8(l0, l1, 0u, 0u);
                aLo = MFMA(A0, bh, aLo); aLo = MFMA(A0, bl, aLo);
                aHi = MFMA(A1, bh, aHi); aHi = MFMA(A1, bl, aHi);
            }
            EPILOGUE();

            // ---------------- Hidden layers 2..4 --------------------------
            #pragma unroll 1
            for (int l = 0; l < 3; ++l) {
                BINIT((l + 1) * 64);
                #pragma unroll
                for (int kk = 0; kk < 4; ++kk) {
                    s16x8 A0 = *(const s16x8*)&sWH[((l * 2 + 0) * 4 + kk) * 512 + lane * 8];
                    s16x8 A1 = *(const s16x8*)&sWH[((l * 2 + 1) * 4 + kk) * 512 + lane * 8];
                    s16x8 bh = mk8(Bh[kk][0], Bh[kk][1], Bh[kk][2], Bh[kk][3]);
                    s16x8 bl = mk8(Bl[kk][0], Bl[kk][1], Bl[kk][2], Bl[kk][3]);
                    aLo = MFMA(A0, bh, aLo); aLo = MFMA(A0, bl, aLo);
                    aHi = MFMA(A1, bh, aHi); aHi = MFMA(A1, bl, aHi);
                }
                EPILOGUE();
            }

            // ---------------- Output layer (M=12 padded to 32) ------------
            f32x16 o;
            #pragma unroll
            for (int i = 0; i < 16; ++i) o[i] = 0.f;
            #pragma unroll
            for (int kk = 0; kk < 4; ++kk) {
                s16x8 A5 = *(const s16x8*)&sW5[kk * 512 + lane * 8];
                s16x8 bh = mk8(Bh[kk][0], Bh[kk][1], Bh[kk][2], Bh[kk][3]);
                s16x8 bl = mk8(Bl[kk][0], Bl[kk][1], Bl[kk][2], Bl[kk][3]);
                o = MFMA(A5, bh, o); o = MFMA(A5, bl, o);
            }
            // col r=4p+s, s>0 -> out[pt][s-1][m]; m = (i&3)+8*(i>>2)+4*hi
            if (!is0) {
                int pt = base + nt * 8 + pq;
                if (pt < N) {
                    float* ob = out + (size_t)pt * 36 + (s - 1) * 12;
                    if (hi == 0) {
                        *(f32x4*)(ob + 0) = (f32x4){o[0], o[1], o[2], o[3]};
                        *(f32x4*)(ob + 8) = (f32x4){o[4], o[5], o[6], o[7]};
                    } else {
                        *(f32x4*)(ob + 4) = (f32x4){o[0], o[1], o[2], o[3]};
                    }
                }
            }
        }
    }
#undef SILU16
#undef EPILOGUE
#undef BINIT
}

extern "C" void kernel_launch(void* const* d_in, const int* in_sizes, int n_in,
                              void* d_out, int out_size, void* d_ws, size_t ws_size,
                              hipStream_t stream) {
    const float* x  = (const float*)d_in[0];
    const float* W1 = (const float*)d_in[1];
    const float* b1 = (const float*)d_in[2];
    const float* W2 = (const float*)d_in[3];
    const float* b2 = (const float*)d_in[4];
    const float* W3 = (const float*)d_in[5];
    const float* b3 = (const float*)d_in[6];
    const float* W4 = (const float*)d_in[7];
    const float* b4 = (const float*)d_in[8];
    const float* W5 = (const float*)d_in[9];
    // d_in[10] = b5: unused (bias has zero Jacobian)
    float* out = (float*)d_out;

    const int N = in_sizes[0] / 3;
    const int ntiles = (N + 15) / 16;
    const int blocks = 2048;
    PartialDerivatives_mfma<<<blocks, THREADS, 0, stream>>>(
        x, W1, b1, W2, b2, W3, b3, W4, b4, W5, out, N, ntiles);
}